// Round 13
// baseline (185.265 us; speedup 1.0000x reference)
//
#include <hip/hip_runtime.h>
#include <hip/hip_bf16.h>

typedef __attribute__((ext_vector_type(8))) short bf16x8;
typedef __attribute__((ext_vector_type(8))) unsigned short u16x8;
typedef __attribute__((ext_vector_type(16))) float f32x16;
typedef __attribute__((ext_vector_type(4))) unsigned int u32x4;

#define MFMA32(a, b, c) __builtin_amdgcn_mfma_f32_32x32x16_bf16(a, b, c, 0, 0, 0)

constexpr int NSEQ = 8192;
constexpr int NH   = 8;
constexpr int DIM  = 64;
constexpr int KVB  = 64;
constexpr int NT   = NSEQ / KVB;         // 128 tiles
constexpr int NTH  = NT / 2;             // 64 tiles per KV-half
constexpr int SLAB = KVB * DIM;          // 4096 ushorts = 8KB per tile slab
constexpr float SCL2 = 0.18033688011112042f;  // 0.125 * log2(e)

__device__ __forceinline__ unsigned cvt_pk(float lo, float hi) {
    unsigned r;
    asm("v_cvt_pk_bf16_f32 %0, %1, %2" : "=v"(r) : "v"(lo), "v"(hi));
    return r;
}
__device__ __forceinline__ float exp2f_fast(float x) {
    float r;
    asm("v_exp_f32 %0, %1" : "=v"(r) : "v"(x));
    return r;
}
// safe ONLY with provably-distinct operands (distinct live values)
__device__ __forceinline__ void pl32swap(unsigned& a, unsigned& b) {
    asm("v_permlane32_swap_b32 %0, %1" : "+v"(a), "+v"(b));
}
// async global->LDS, 16B per lane; lds ptr must be wave-uniform (m104)
__device__ __forceinline__ void gload16(const unsigned short* g, unsigned short* l) {
    __builtin_amdgcn_global_load_lds(
        (const __attribute__((address_space(1))) void*)g,
        (__attribute__((address_space(3))) void*)l,
        16, 0, 0);
}
// (fallback kernel only) XOR-swizzled LDS index for [row][64] bf16 tiles
__device__ __forceinline__ int swz(int row, int col) {
    return row * 64 + ((((col >> 3) ^ row) & 7) << 3) + (col & 7);
}

// ============ prep: fp32 K/V -> bf16 slabs in FRAGMENT-READ order ============
// Slab = 8 wave-instructions x 64 lanes x 16B, linear:
//   K chunk(instr=kh*4+kd, lane): K[t*64 + kh*32 + (lane&31)][h][kd*16 + (lane>>5)*8 + 0..7]
//   V chunk(instr=vh*4+ks, lane): V[t*64 + ks*16 + (lane>>5)*8 + 0..7][h][vh*32 + (lane&31)]
__global__ __launch_bounds__(256, 4)
void prep_kernel(const float* __restrict__ Kg, const float* __restrict__ Vg,
                 unsigned short* __restrict__ Kws, unsigned short* __restrict__ Vws) {
    __shared__ float Vf[64][65];
    const int tid = threadIdx.x;
    const int bid = blockIdx.x;
    if (bid < 1024) {  // ---- K ----
        const int h = bid >> 7, t = bid & 127;
        unsigned short* dst = Kws + (size_t)bid * SLAB;
#pragma unroll
        for (int j = 0; j < 2; ++j) {
            const int m = tid * 2 + j;                 // chunk 0..511
            const int instr = m >> 6, ln = m & 63;
            const int kh = instr >> 2, kd = instr & 3;
            const int row = t * 64 + kh * 32 + (ln & 31);
            const int col = kd * 16 + (ln >> 5) * 8;
            const float* src = Kg + ((size_t)row * NH + h) * DIM + col;
            float4 a = ((const float4*)src)[0];
            float4 b = ((const float4*)src)[1];
            u32x4 w;
            w[0] = cvt_pk(a.x, a.y); w[1] = cvt_pk(a.z, a.w);
            w[2] = cvt_pk(b.x, b.y); w[3] = cvt_pk(b.z, b.w);
            *(u32x4*)(dst + m * 8) = w;
        }
    } else {           // ---- V: transpose via LDS ----
        const int hb = bid - 1024;
        const int h = hb >> 7, t = hb & 127;
        const int key = tid >> 2, dc = (tid & 3) * 16;
        const float* src = Vg + ((size_t)(t * 64 + key) * NH + h) * DIM + dc;
#pragma unroll
        for (int i = 0; i < 4; ++i) {
            float4 a = ((const float4*)src)[i];
            Vf[key][dc + i * 4 + 0] = a.x; Vf[key][dc + i * 4 + 1] = a.y;
            Vf[key][dc + i * 4 + 2] = a.z; Vf[key][dc + i * 4 + 3] = a.w;
        }
        __syncthreads();
        unsigned short* dst = Vws + (size_t)hb * SLAB;
#pragma unroll
        for (int j = 0; j < 2; ++j) {
            const int m = tid * 2 + j;
            const int instr = m >> 6, ln = m & 63;
            const int vh = instr >> 2, ks = instr & 3;
            const int d  = vh * 32 + (ln & 31);
            const int k0 = ks * 16 + (ln >> 5) * 8;
            u32x4 w;
            w[0] = cvt_pk(Vf[k0 + 0][d], Vf[k0 + 1][d]);
            w[1] = cvt_pk(Vf[k0 + 2][d], Vf[k0 + 3][d]);
            w[2] = cvt_pk(Vf[k0 + 4][d], Vf[k0 + 5][d]);
            w[3] = cvt_pk(Vf[k0 + 6][d], Vf[k0 + 7][d]);
            *(u32x4*)(dst + m * 8) = w;
        }
    }
}

// ============ main: r12 structure + global_load_lds direct staging ============
__global__ __launch_bounds__(256, 2)
void fa_kernel(const float* __restrict__ Qg, const unsigned short* __restrict__ Kws,
               const unsigned short* __restrict__ Vws, float* __restrict__ Og) {
    __shared__ unsigned short KVb[2][2][2][SLAB];  // [K/V][half][dbuf][slab] = 64KB
    __shared__ float mrgML[2][2][128];             // [grp][m/l][row]

    const int tid  = threadIdx.x;
    const int lane = tid & 63;
    const int wave = tid >> 6;       // 0..3
    const int la31 = lane & 31;
    const int hi   = lane >> 5;
    const int head  = blockIdx.x & 7;    // head pinned per XCD (4MB KV slab = XCD L2)
    const int qtile = blockIdx.x >> 3;
    const int fragoff = lane * 8;

    // block = 256 threads = 4 waves = 2 halves x 2 q-waves
    const int half_f  = wave >> 1;
    const int qv_f    = wave & 1;
    const int qbase_f = qtile * 128 + qv_f * 64;
    const int halftid_f = tid & 127;   // 2 waves per half stage the slab

    // ---- persistent Q fragments for both groups ----
    bf16x8 qf[2][4];
#pragma unroll
    for (int g = 0; g < 2; ++g)
#pragma unroll
        for (int kd = 0; kd < 4; ++kd) {
            const float* qp = Qg + ((size_t)(qbase_f + g * 32 + la31) * NH + head) * DIM + kd * 16 + hi * 8;
            float4 a = ((const float4*)qp)[0];
            float4 b = ((const float4*)qp)[1];
            u32x4 w;
            w[0] = cvt_pk(a.x * SCL2, a.y * SCL2);
            w[1] = cvt_pk(a.z * SCL2, a.w * SCL2);
            w[2] = cvt_pk(b.x * SCL2, b.y * SCL2);
            w[3] = cvt_pk(b.z * SCL2, b.w * SCL2);
            qf[g][kd] = __builtin_bit_cast(bf16x8, w);
        }

    // per-lane global source (halftid*16B baked in); LDS dest is wave-uniform + lane*16B
    const unsigned short* ksl = Kws + ((size_t)head * NT + (size_t)half_f * NTH) * SLAB + halftid_f * 8;
    const unsigned short* vsl = Vws + ((size_t)head * NT + (size_t)half_f * NTH) * SLAB + halftid_f * 8;

    f32x16 oacc[2][2];
#pragma unroll
    for (int g = 0; g < 2; ++g)
#pragma unroll
        for (int nt = 0; nt < 2; ++nt)
#pragma unroll
            for (int i = 0; i < 16; ++i) oacc[g][nt][i] = 0.f;
    float m_run[2] = {-1e30f, -1e30f}, l_run[2] = {0.f, 0.f};

    // ---- async stage of one tile into buf b: 8 x global_load_lds per wave ----
    auto stage = [&](int b) {
        unsigned short* kb = &KVb[0][half_f][b][qv_f * 512];   // wave-uniform base
        unsigned short* vb = &KVb[1][half_f][b][qv_f * 512];
        gload16(ksl,        kb);        gload16(ksl + 1024, kb + 1024);
        gload16(ksl + 2048, kb + 2048); gload16(ksl + 3072, kb + 3072);
        gload16(vsl,        vb);        gload16(vsl + 1024, vb + 1024);
        gload16(vsl + 2048, vb + 2048); gload16(vsl + 3072, vb + 3072);
    };

    // prologue: issue tile 0 into buf 0
    stage(0);
    ksl += SLAB; vsl += SLAB;

    for (int t = 0; t < NTH; ++t) {
        const int cur = t & 1;
        __syncthreads();   // drains vmcnt: buf[cur] (tile t) landed; all reads of buf[cur^1] done
        if (t + 1 < NTH) {
            stage(cur ^ 1);            // async: lands during this tile's compute
            ksl += SLAB; vsl += SLAB;
        }
        const unsigned short* Kbase = &KVb[0][half_f][cur][0];
        const unsigned short* Vbase = &KVb[1][half_f][cur][0];

        // ---- QK^T for both groups: 8 ds_read, 16 MFMA ----
        f32x16 s00, s01, s10, s11;   // [grp][kh]
#pragma unroll
        for (int i = 0; i < 16; ++i) { s00[i] = 0.f; s01[i] = 0.f; s10[i] = 0.f; s11[i] = 0.f; }
        __builtin_amdgcn_s_setprio(1);
#pragma unroll
        for (int kd = 0; kd < 4; ++kd) {
            bf16x8 k0 = *(const bf16x8*)(Kbase + kd * 512 + fragoff);
            bf16x8 k1 = *(const bf16x8*)(Kbase + (4 + kd) * 512 + fragoff);
            s00 = MFMA32(k0, qf[0][kd], s00);
            s01 = MFMA32(k1, qf[0][kd], s01);
            s10 = MFMA32(k0, qf[1][kd], s10);
            s11 = MFMA32(k1, qf[1][kd], s11);
        }
        __builtin_amdgcn_s_setprio(0);

        // ---- per-group max + defer-max rescale ----
#pragma unroll
        for (int g = 0; g < 2; ++g) {
            const f32x16& a = g ? s10 : s00;
            const f32x16& b = g ? s11 : s01;
            float pmv[16];
#pragma unroll
            for (int i = 0; i < 16; ++i) pmv[i] = fmaxf(a[i], b[i]);
#pragma unroll
            for (int st = 8; st >= 1; st >>= 1)
#pragma unroll
                for (int i = 0; i < 8; ++i)
                    if (i < st) pmv[i] = fmaxf(pmv[i], pmv[i + st]);
            float pm = pmv[0];
            pm = fmaxf(pm, __shfl_xor(pm, 32));
            if (__any(pm > m_run[g] + 8.f)) {
                float mnew = fmaxf(m_run[g], pm);
                float corr = exp2f_fast(m_run[g] - mnew);
                m_run[g] = mnew;
                l_run[g] *= corr;
#pragma unroll
                for (int i = 0; i < 16; ++i) { oacc[g][0][i] *= corr; oacc[g][1][i] *= corr; }
            }
        }

        // ---- per key-block: exp+pack both groups, then 8 shared-V MFMAs ----
#pragma unroll
        for (int kb2 = 0; kb2 < 2; ++kb2) {
            bf16x8 frg[2][2];
#pragma unroll
            for (int g = 0; g < 2; ++g) {
                const f32x16& s = g ? (kb2 ? s11 : s10) : (kb2 ? s01 : s00);
                float p[16];
#pragma unroll
                for (int i = 0; i < 16; ++i) p[i] = exp2f_fast(s[i] - m_run[g]);
                float ts[8];
#pragma unroll
                for (int i = 0; i < 8; ++i) ts[i] = p[i] + p[i + 8];
#pragma unroll
                for (int i = 0; i < 4; ++i) ts[i] += ts[i + 4];
                l_run[g] += (ts[0] + ts[1]) + (ts[2] + ts[3]);
                unsigned A[8];
#pragma unroll
                for (int j = 0; j < 8; ++j) A[j] = cvt_pk(p[2 * j], p[2 * j + 1]);
                pl32swap(A[0], A[2]); pl32swap(A[1], A[3]);
                pl32swap(A[4], A[6]); pl32swap(A[5], A[7]);
                u32x4 f0v; f0v[0] = A[0]; f0v[1] = A[1]; f0v[2] = A[2]; f0v[3] = A[3];
                u32x4 f1v; f1v[0] = A[4]; f1v[1] = A[5]; f1v[2] = A[6]; f1v[3] = A[7];
                frg[g][0] = __builtin_bit_cast(bf16x8, f0v);
                frg[g][1] = __builtin_bit_cast(bf16x8, f1v);
            }
            __builtin_amdgcn_s_setprio(1);
#pragma unroll
            for (int ks2 = 0; ks2 < 2; ++ks2) {
                const int ksg = kb2 * 2 + ks2;
                bf16x8 vf0 = *(const bf16x8*)(Vbase + ksg * 512 + fragoff);
                bf16x8 vf1 = *(const bf16x8*)(Vbase + (4 + ksg) * 512 + fragoff);
                oacc[0][0] = MFMA32(vf0, frg[0][ks2], oacc[0][0]);
                oacc[0][1] = MFMA32(vf1, frg[0][ks2], oacc[0][1]);
                oacc[1][0] = MFMA32(vf0, frg[1][ks2], oacc[1][0]);
                oacc[1][1] = MFMA32(vf1, frg[1][ks2], oacc[1][1]);
            }
            __builtin_amdgcn_s_setprio(0);
        }
    }

    // ---- merge the two KV-halves (max-aware); mrgO reuses the 64KB KV buffer ----
    __syncthreads();
    float* mrgO = (float*)&KVb[0][0][0][0];  // [hi][val 0..31][row 0..127]
    const int row0 = qv_f * 64;              // + g*32 + la31
    if (half_f) {
#pragma unroll
        for (int g = 0; g < 2; ++g) {
            const int row = row0 + g * 32 + la31;
#pragma unroll
            for (int nt = 0; nt < 2; ++nt)
#pragma unroll
                for (int i = 0; i < 16; ++i)
                    mrgO[hi * 4096 + (nt * 16 + i) * 128 + row] = oacc[g][nt][i];
            mrgML[g][0][qv_f * 64 + lane] = m_run[g];   // per-lane m (pair lanes equal)
            mrgML[g][1][qv_f * 64 + lane] = l_run[g];
        }
    }
    __syncthreads();
    if (!half_f) {
#pragma unroll
        for (int g = 0; g < 2; ++g) {
            const int row = row0 + g * 32 + la31;
            const float m1 = mrgML[g][0][qv_f * 64 + lane];
            const float l1 = mrgML[g][1][qv_f * 64 + lane];
            const float mnew = fmaxf(m_run[g], m1);
            const float c0 = exp2f_fast(m_run[g] - mnew);
            const float c1 = exp2f_fast(m1 - mnew);
            float lt = l_run[g] * c0 + l1 * c1;
#pragma unroll
            for (int nt = 0; nt < 2; ++nt)
#pragma unroll
                for (int i = 0; i < 16; ++i)
                    oacc[g][nt][i] = oacc[g][nt][i] * c0 + mrgO[hi * 4096 + (nt * 16 + i) * 128 + row] * c1;
            const float l_tot = lt + __shfl_xor(lt, 32);
            const float inv = __builtin_amdgcn_rcpf(l_tot);
            float* obase = Og + ((size_t)(qtile * 128 + row) * NH + head) * DIM;
#pragma unroll
            for (int nt = 0; nt < 2; ++nt)
#pragma unroll
                for (int rq = 0; rq < 4; ++rq) {
                    float4 o;
                    o.x = oacc[g][nt][rq * 4 + 0] * inv;
                    o.y = oacc[g][nt][rq * 4 + 1] * inv;
                    o.z = oacc[g][nt][rq * 4 + 2] * inv;
                    o.w = oacc[g][nt][rq * 4 + 3] * inv;
                    *(float4*)(obase + nt * 32 + rq * 8 + hi * 4) = o;
                }
        }
    }
}

// ============ fallback (round-4 proven kernel) if ws too small ============
__global__ __launch_bounds__(256, 2)
void fb_kernel(const float* __restrict__ Qg, const float* __restrict__ Kg,
               const float* __restrict__ Vg, float* __restrict__ Og) {
    __shared__ unsigned short Kl[KVB][DIM];
    __shared__ unsigned short Vt[DIM][KVB];
    unsigned short* Kbase = &Kl[0][0];
    unsigned short* Vbase = &Vt[0][0];
    const int tid  = threadIdx.x;
    const int lane = tid & 63;
    const int wave = tid >> 6;
    const int la31 = lane & 31;
    const int hi   = lane >> 5;
    const int head  = blockIdx.x & 7;
    const int qtile = blockIdx.x >> 3;
    const int q     = qtile * 128 + wave * 32 + la31;
    bf16x8 qf[4];
#pragma unroll
    for (int kd = 0; kd < 4; ++kd) {
        const float* qp = Qg + ((size_t)q * NH + head) * DIM + kd * 16 + hi * 8;
        float4 a = ((const float4*)qp)[0];
        float4 b = ((const float4*)qp)[1];
        u32x4 w;
        w[0] = cvt_pk(a.x * SCL2, a.y * SCL2);
        w[1] = cvt_pk(a.z * SCL2, a.w * SCL2);
        w[2] = cvt_pk(b.x * SCL2, b.y * SCL2);
        w[3] = cvt_pk(b.z * SCL2, b.w * SCL2);
        qf[kd] = __builtin_bit_cast(bf16x8, w);
    }
    const int ksrow = tid & 63;
    const int kscol = (tid >> 6) * 16;
    const int vpair = tid & 31;
    const int vcg   = tid >> 5;
    const float* kptr  = Kg + ((size_t)ksrow * NH + head) * DIM + kscol;
    const float* vptr0 = Vg + ((size_t)(2 * vpair) * NH + head) * DIM + vcg * 8;
    const float* vptr1 = vptr0 + NH * DIM;
    constexpr size_t STRIDE = (size_t)KVB * NH * DIM;
    const int kIdx0 = swz(ksrow, kscol);
    const int kIdx1 = swz(ksrow, kscol + 8);
    f32x16 oacc[2];
#pragma unroll
    for (int nt = 0; nt < 2; ++nt)
#pragma unroll
        for (int i = 0; i < 16; ++i) oacc[nt][i] = 0.f;
    float m_run = -1e30f, l_run = 0.f;
    float4 kr0 = ((const float4*)kptr)[0], kr1 = ((const float4*)kptr)[1];
    float4 kr2 = ((const float4*)kptr)[2], kr3 = ((const float4*)kptr)[3];
    float4 va0 = ((const float4*)vptr0)[0], va1 = ((const float4*)vptr0)[1];
    float4 vb0 = ((const float4*)vptr1)[0], vb1 = ((const float4*)vptr1)[1];
    kptr += STRIDE; vptr0 += STRIDE; vptr1 += STRIDE;
    for (int t = 0; t < NT; ++t) {
        __syncthreads();
        {
            u32x4 w;
            w[0] = cvt_pk(kr0.x, kr0.y); w[1] = cvt_pk(kr0.z, kr0.w);
            w[2] = cvt_pk(kr1.x, kr1.y); w[3] = cvt_pk(kr1.z, kr1.w);
            *(u32x4*)(Kbase + kIdx0) = w;
            w[0] = cvt_pk(kr2.x, kr2.y); w[1] = cvt_pk(kr2.z, kr2.w);
            w[2] = cvt_pk(kr3.x, kr3.y); w[3] = cvt_pk(kr3.z, kr3.w);
            *(u32x4*)(Kbase + kIdx1) = w;
        }
        {
            *(unsigned*)(Vbase + swz(vcg * 8 + 0, 2 * vpair)) = cvt_pk(va0.x, vb0.x);
            *(unsigned*)(Vbase + swz(vcg * 8 + 1, 2 * vpair)) = cvt_pk(va0.y, vb0.y);
            *(unsigned*)(Vbase + swz(vcg * 8 + 2, 2 * vpair)) = cvt_pk(va0.z, vb0.z);
            *(unsigned*)(Vbase + swz(vcg * 8 + 3, 2 * vpair)) = cvt_pk(va0.w, vb0.w);
            *(unsigned*)(Vbase + swz(vcg * 8 + 4, 2 * vpair)) = cvt_pk(va1.x, vb1.x);
            *(unsigned*)(Vbase + swz(vcg * 8 + 5, 2 * vpair)) = cvt_pk(va1.y, vb1.y);
            *(unsigned*)(Vbase + swz(vcg * 8 + 6, 2 * vpair)) = cvt_pk(va1.z, vb1.z);
            *(unsigned*)(Vbase + swz(vcg * 8 + 7, 2 * vpair)) = cvt_pk(va1.w, vb1.w);
        }
        __syncthreads();
        if (t + 1 < NT) {
            kr0 = ((const float4*)kptr)[0]; kr1 = ((const float4*)kptr)[1];
            kr2 = ((const float4*)kptr)[2]; kr3 = ((const float4*)kptr)[3];
            va0 = ((const float4*)vptr0)[0]; va1 = ((const float4*)vptr0)[1];
            vb0 = ((const float4*)vptr1)[0]; vb1 = ((const float4*)vptr1)[1];
            kptr += STRIDE; vptr0 += STRIDE; vptr1 += STRIDE;
        }
        f32x16 s0, s1;
#pragma unroll
        for (int i = 0; i < 16; ++i) { s0[i] = 0.f; s1[i] = 0.f; }
        __builtin_amdgcn_s_setprio(1);
#pragma unroll
        for (int kd = 0; kd < 4; ++kd) {
            bf16x8 k0 = *(const bf16x8*)(Kbase + swz(la31, kd * 16 + hi * 8));
            bf16x8 k1 = *(const bf16x8*)(Kbase + swz(32 + la31, kd * 16 + hi * 8));
            s0 = MFMA32(k0, qf[kd], s0);
            s1 = MFMA32(k1, qf[kd], s1);
        }
        __builtin_amdgcn_s_setprio(0);
        float pmv[16];
#pragma unroll
        for (int i = 0; i < 16; ++i) pmv[i] = fmaxf(s0[i], s1[i]);
#pragma unroll
        for (int st = 8; st >= 1; st >>= 1)
#pragma unroll
            for (int i = 0; i < 8; ++i)
                if (i < st) pmv[i] = fmaxf(pmv[i], pmv[i + st]);
        float pm = pmv[0];
        pm = fmaxf(pm, __shfl_xor(pm, 32));
        if (__any(pm > m_run + 8.f)) {
            float mnew = fmaxf(m_run, pm);
            float corr = exp2f_fast(m_run - mnew);
            m_run = mnew;
            l_run *= corr;
#pragma unroll
            for (int i = 0; i < 16; ++i) { oacc[0][i] *= corr; oacc[1][i] *= corr; }
        }
#pragma unroll
        for (int kb = 0; kb < 2; ++kb) {
            const f32x16& s = kb ? s1 : s0;
            float p[16];
#pragma unroll
            for (int i = 0; i < 16; ++i) p[i] = exp2f_fast(s[i] - m_run);
            float ts[8];
#pragma unroll
            for (int i = 0; i < 8; ++i) ts[i] = p[i] + p[i + 8];
#pragma unroll
            for (int i = 0; i < 4; ++i) ts[i] += ts[i + 4];
            l_run += (ts[0] + ts[1]) + (ts[2] + ts[3]);
            unsigned A[8];
#pragma unroll
            for (int j = 0; j < 8; ++j) A[j] = cvt_pk(p[2 * j], p[2 * j + 1]);
            pl32swap(A[0], A[2]); pl32swap(A[1], A[3]);
            pl32swap(A[4], A[6]); pl32swap(A[5], A[7]);
            u32x4 f0v; f0v[0] = A[0]; f0v[1] = A[1]; f0v[2] = A[2]; f0v[3] = A[3];
            u32x4 f1v; f1v[0] = A[4]; f1v[1] = A[5]; f1v[2] = A[6]; f1v[3] = A[7];
            bf16x8 frag[2] = { __builtin_bit_cast(bf16x8, f0v), __builtin_bit_cast(bf16x8, f1v) };
            __builtin_amdgcn_s_setprio(1);
#pragma unroll
            for (int ksl = 0; ksl < 2; ++ksl) {
                const int ksg = kb * 2 + ksl;
                bf16x8 vf0 = *(const bf16x8*)(Vbase + swz(la31, ksg * 16 + hi * 8));
                bf16x8 vf1 = *(const bf16x8*)(Vbase + swz(32 + la31, ksg * 16 + hi * 8));
                oacc[0] = MFMA32(vf0, frag[ksl], oacc[0]);
                oacc[1] = MFMA32(vf1, frag[ksl], oacc[1]);
            }
            __builtin_amdgcn_s_setprio(0);
        }
    }
    {
        float l_tot = l_run + __shfl_xor(l_run, 32);
        float inv = __builtin_amdgcn_rcpf(l_tot);
        float* obase = Og + ((size_t)q * NH + head) * DIM;
#pragma unroll
        for (int nt = 0; nt < 2; ++nt)
#pragma unroll
            for (int rq = 0; rq < 4; ++rq) {
                float4 o;
                o.x = oacc[nt][rq * 4 + 0] * inv;
                o.y = oacc[nt][rq * 4 + 1] * inv;
                o.z = oacc[nt][rq * 4 + 2] * inv;
                o.w = oacc[nt][rq * 4 + 3] * inv;
                *(float4*)(obase + nt * 32 + rq * 8 + hi * 4) = o;
            }
    }
}

extern "C" void kernel_launch(void* const* d_in, const int* in_sizes, int n_in,
                              void* d_out, int out_size, void* d_ws, size_t ws_size,
                              hipStream_t stream) {
    const float* q = (const float*)d_in[0];
    const float* k = (const float*)d_in[1];
    const float* v = (const float*)d_in[2];
    float* out = (float*)d_out;
    constexpr size_t KV_WS = 2ull * NH * NT * SLAB * sizeof(unsigned short);  // 16.78 MB
    if (ws_size >= KV_WS) {
        unsigned short* Kws = (unsigned short*)d_ws;
        unsigned short* Vws = Kws + (size_t)NH * NT * SLAB;
        hipLaunchKernelGGL(prep_kernel, dim3(2048), dim3(256), 0, stream, k, v, Kws, Vws);
        // block = 256 threads = 4 waves = 2 KV-halves x 2 q-waves x 64 q-rows (QB=128)
        hipLaunchKernelGGL(fa_kernel, dim3(512), dim3(256), 0, stream, q, Kws, Vws, out);
    } else {
        hipLaunchKernelGGL(fb_kernel, dim3(512), dim3(256), 0, stream, q, k, v, out);
    }
}

// Round 14
// 182.666 us; speedup vs baseline: 1.0142x; 1.0142x over previous
//
#include <hip/hip_runtime.h>
#include <hip/hip_bf16.h>

typedef __attribute__((ext_vector_type(8))) short bf16x8;
typedef __attribute__((ext_vector_type(8))) unsigned short u16x8;
typedef __attribute__((ext_vector_type(16))) float f32x16;
typedef __attribute__((ext_vector_type(4))) unsigned int u32x4;

#define MFMA32(a, b, c) __builtin_amdgcn_mfma_f32_32x32x16_bf16(a, b, c, 0, 0, 0)

constexpr int NSEQ = 8192;
constexpr int NH   = 8;
constexpr int DIM  = 64;
constexpr int KVB  = 64;
constexpr int NT   = NSEQ / KVB;         // 128 tiles
constexpr int NTH  = NT / 2;             // 64 tiles per KV-half
constexpr int SLAB = KVB * DIM;          // 4096 ushorts = 8KB per tile slab
constexpr float SCL2 = 0.18033688011112042f;  // 0.125 * log2(e)

__device__ __forceinline__ unsigned cvt_pk(float lo, float hi) {
    unsigned r;
    asm("v_cvt_pk_bf16_f32 %0, %1, %2" : "=v"(r) : "v"(lo), "v"(hi));
    return r;
}
__device__ __forceinline__ float exp2f_fast(float x) {
    float r;
    asm("v_exp_f32 %0, %1" : "=v"(r) : "v"(x));
    return r;
}
// safe ONLY with provably-distinct operands (distinct live values)
__device__ __forceinline__ void pl32swap(unsigned& a, unsigned& b) {
    asm("v_permlane32_swap_b32 %0, %1" : "+v"(a), "+v"(b));
}
// (fallback kernel only) XOR-swizzled LDS index for [row][64] bf16 tiles
__device__ __forceinline__ int swz(int row, int col) {
    return row * 64 + ((((col >> 3) ^ row) & 7) << 3) + (col & 7);
}

// ============ prep: fp32 K/V -> bf16 slabs in FRAGMENT-READ order ============
// Slab = 8 wave-instructions x 64 lanes x 16B, linear:
//   K chunk(instr=kh*4+kd, lane): K[t*64 + kh*32 + (lane&31)][h][kd*16 + (lane>>5)*8 + 0..7]
//   V chunk(instr=vh*4+ks, lane): V[t*64 + ks*16 + (lane>>5)*8 + 0..7][h][vh*32 + (lane&31)]
__global__ __launch_bounds__(256, 4)
void prep_kernel(const float* __restrict__ Kg, const float* __restrict__ Vg,
                 unsigned short* __restrict__ Kws, unsigned short* __restrict__ Vws) {
    __shared__ float Vf[64][65];
    const int tid = threadIdx.x;
    const int bid = blockIdx.x;
    if (bid < 1024) {  // ---- K ----
        const int h = bid >> 7, t = bid & 127;
        unsigned short* dst = Kws + (size_t)bid * SLAB;
#pragma unroll
        for (int j = 0; j < 2; ++j) {
            const int m = tid * 2 + j;                 // chunk 0..511
            const int instr = m >> 6, ln = m & 63;
            const int kh = instr >> 2, kd = instr & 3;
            const int row = t * 64 + kh * 32 + (ln & 31);
            const int col = kd * 16 + (ln >> 5) * 8;
            const float* src = Kg + ((size_t)row * NH + h) * DIM + col;
            float4 a = ((const float4*)src)[0];
            float4 b = ((const float4*)src)[1];
            u32x4 w;
            w[0] = cvt_pk(a.x, a.y); w[1] = cvt_pk(a.z, a.w);
            w[2] = cvt_pk(b.x, b.y); w[3] = cvt_pk(b.z, b.w);
            *(u32x4*)(dst + m * 8) = w;
        }
    } else {           // ---- V: transpose via LDS ----
        const int hb = bid - 1024;
        const int h = hb >> 7, t = hb & 127;
        const int key = tid >> 2, dc = (tid & 3) * 16;
        const float* src = Vg + ((size_t)(t * 64 + key) * NH + h) * DIM + dc;
#pragma unroll
        for (int i = 0; i < 4; ++i) {
            float4 a = ((const float4*)src)[i];
            Vf[key][dc + i * 4 + 0] = a.x; Vf[key][dc + i * 4 + 1] = a.y;
            Vf[key][dc + i * 4 + 2] = a.z; Vf[key][dc + i * 4 + 3] = a.w;
        }
        __syncthreads();
        unsigned short* dst = Vws + (size_t)hb * SLAB;
#pragma unroll
        for (int j = 0; j < 2; ++j) {
            const int m = tid * 2 + j;
            const int instr = m >> 6, ln = m & 63;
            const int vh = instr >> 2, ks = instr & 3;
            const int d  = vh * 32 + (ln & 31);
            const int k0 = ks * 16 + (ln >> 5) * 8;
            u32x4 w;
            w[0] = cvt_pk(Vf[k0 + 0][d], Vf[k0 + 1][d]);
            w[1] = cvt_pk(Vf[k0 + 2][d], Vf[k0 + 3][d]);
            w[2] = cvt_pk(Vf[k0 + 4][d], Vf[k0 + 5][d]);
            w[3] = cvt_pk(Vf[k0 + 6][d], Vf[k0 + 7][d]);
            *(u32x4*)(dst + m * 8) = w;
        }
    }
}

// ============ main: 4 waves = 2 KV-halves x 2 q-waves x 64 q-rows (2 groups) ============
__global__ __launch_bounds__(512, 2)
void fa_kernel(const float* __restrict__ Qg, const unsigned short* __restrict__ Kws,
               const unsigned short* __restrict__ Vws, float* __restrict__ Og) {
    __shared__ unsigned short KVb[2][2][2][SLAB];  // [K/V][half][dbuf][slab] = 64KB
    __shared__ float mrgML[2][2][256];             // [grp][m/l][row]

    const int tid  = threadIdx.x;
    const int lane = tid & 63;
    const int wave = tid >> 6;       // 0..3
    const int la31 = lane & 31;
    const int hi   = lane >> 5;
    const int head  = blockIdx.x & 7;    // head pinned per XCD (4MB KV slab = XCD L2)
    const int qtile = blockIdx.x >> 3;
    const int fragoff = lane * 8;

    // block = 256 threads = 4 waves = 2 halves x 2 q-waves. half = wave>>1, qv = wave&1.
    const int half_f  = wave >> 1;
    const int qv_f    = wave & 1;
    const int qbase_f = qtile * 128 + qv_f * 64;
    const int halftid_f = tid & 127;   // 2 waves per half stage the slab

    // ---- persistent Q fragments for both groups ----
    bf16x8 qf[2][4];
#pragma unroll
    for (int g = 0; g < 2; ++g)
#pragma unroll
        for (int kd = 0; kd < 4; ++kd) {
            const float* qp = Qg + ((size_t)(qbase_f + g * 32 + la31) * NH + head) * DIM + kd * 16 + hi * 8;
            float4 a = ((const float4*)qp)[0];
            float4 b = ((const float4*)qp)[1];
            u32x4 w;
            w[0] = cvt_pk(a.x * SCL2, a.y * SCL2);
            w[1] = cvt_pk(a.z * SCL2, a.w * SCL2);
            w[2] = cvt_pk(b.x * SCL2, b.y * SCL2);
            w[3] = cvt_pk(b.z * SCL2, b.w * SCL2);
            qf[g][kd] = __builtin_bit_cast(bf16x8, w);
        }

    // staging: 128 threads per half stage 8KB K + 8KB V per tile (4 chunks each)
    const unsigned short* ksl = Kws + ((size_t)head * NT + (size_t)half_f * NTH) * SLAB + halftid_f * 8;
    const unsigned short* vsl = Vws + ((size_t)head * NT + (size_t)half_f * NTH) * SLAB + halftid_f * 8;

    f32x16 oacc[2][2];
#pragma unroll
    for (int g = 0; g < 2; ++g)
#pragma unroll
        for (int nt = 0; nt < 2; ++nt)
#pragma unroll
            for (int i = 0; i < 16; ++i) oacc[g][nt][i] = 0.f;
    float m_run[2] = {-1e30f, -1e30f}, l_run[2] = {0.f, 0.f};

    // prologue: load this half's tile 0 (4 chunks K, 4 chunks V per thread)
    u16x8 kr0 = *(const u16x8*)ksl,          kr1 = *(const u16x8*)(ksl + 1024);
    u16x8 kr2 = *(const u16x8*)(ksl + 2048), kr3 = *(const u16x8*)(ksl + 3072);
    u16x8 vr0 = *(const u16x8*)vsl,          vr1 = *(const u16x8*)(vsl + 1024);
    u16x8 vr2 = *(const u16x8*)(vsl + 2048), vr3 = *(const u16x8*)(vsl + 3072);
    ksl += SLAB; vsl += SLAB;

    for (int t = 0; t < NTH; ++t) {
        const int cur = t & 1;
        unsigned short* kw = &KVb[0][half_f][cur][0];
        unsigned short* vw = &KVb[1][half_f][cur][0];
        *(u16x8*)(kw + halftid_f * 8)        = kr0;
        *(u16x8*)(kw + 1024 + halftid_f * 8) = kr1;
        *(u16x8*)(kw + 2048 + halftid_f * 8) = kr2;
        *(u16x8*)(kw + 3072 + halftid_f * 8) = kr3;
        *(u16x8*)(vw + halftid_f * 8)        = vr0;
        *(u16x8*)(vw + 1024 + halftid_f * 8) = vr1;
        *(u16x8*)(vw + 2048 + halftid_f * 8) = vr2;
        *(u16x8*)(vw + 3072 + halftid_f * 8) = vr3;
        __syncthreads();
        if (t + 1 < NTH) {
            kr0 = *(const u16x8*)ksl;          kr1 = *(const u16x8*)(ksl + 1024);
            kr2 = *(const u16x8*)(ksl + 2048); kr3 = *(const u16x8*)(ksl + 3072);
            vr0 = *(const u16x8*)vsl;          vr1 = *(const u16x8*)(vsl + 1024);
            vr2 = *(const u16x8*)(vsl + 2048); vr3 = *(const u16x8*)(vsl + 3072);
            ksl += SLAB; vsl += SLAB;
        }
        const unsigned short* Kbase = &KVb[0][half_f][cur][0];
        const unsigned short* Vbase = &KVb[1][half_f][cur][0];

        // ---- QK^T for both groups: 8 ds_read, 16 MFMA ----
        f32x16 s00, s01, s10, s11;   // [grp][kh]
#pragma unroll
        for (int i = 0; i < 16; ++i) { s00[i] = 0.f; s01[i] = 0.f; s10[i] = 0.f; s11[i] = 0.f; }
        __builtin_amdgcn_s_setprio(1);
#pragma unroll
        for (int kd = 0; kd < 4; ++kd) {
            bf16x8 k0 = *(const bf16x8*)(Kbase + kd * 512 + fragoff);
            bf16x8 k1 = *(const bf16x8*)(Kbase + (4 + kd) * 512 + fragoff);
            s00 = MFMA32(k0, qf[0][kd], s00);
            s01 = MFMA32(k1, qf[0][kd], s01);
            s10 = MFMA32(k0, qf[1][kd], s10);
            s11 = MFMA32(k1, qf[1][kd], s11);
        }
        __builtin_amdgcn_s_setprio(0);

        // ---- per-group max + defer-max rescale ----
#pragma unroll
        for (int g = 0; g < 2; ++g) {
            const f32x16& a = g ? s10 : s00;
            const f32x16& b = g ? s11 : s01;
            float pmv[16];
#pragma unroll
            for (int i = 0; i < 16; ++i) pmv[i] = fmaxf(a[i], b[i]);
#pragma unroll
            for (int st = 8; st >= 1; st >>= 1)
#pragma unroll
                for (int i = 0; i < 8; ++i)
                    if (i < st) pmv[i] = fmaxf(pmv[i], pmv[i + st]);
            float pm = pmv[0];
            pm = fmaxf(pm, __shfl_xor(pm, 32));
            if (__any(pm > m_run[g] + 8.f)) {
                float mnew = fmaxf(m_run[g], pm);
                float corr = exp2f_fast(m_run[g] - mnew);
                m_run[g] = mnew;
                l_run[g] *= corr;
#pragma unroll
                for (int i = 0; i < 16; ++i) { oacc[g][0][i] *= corr; oacc[g][1][i] *= corr; }
            }
        }

        // ---- per key-block: exp+pack both groups, then 8 shared-V MFMAs ----
#pragma unroll
        for (int kb = 0; kb < 2; ++kb) {
            bf16x8 frg[2][2];
#pragma unroll
            for (int g = 0; g < 2; ++g) {
                const f32x16& s = g ? (kb ? s11 : s10) : (kb ? s01 : s00);
                float p[16];
#pragma unroll
                for (int i = 0; i < 16; ++i) p[i] = exp2f_fast(s[i] - m_run[g]);
                float ts[8];
#pragma unroll
                for (int i = 0; i < 8; ++i) ts[i] = p[i] + p[i + 8];
#pragma unroll
                for (int i = 0; i < 4; ++i) ts[i] += ts[i + 4];
                l_run[g] += (ts[0] + ts[1]) + (ts[2] + ts[3]);
                unsigned A[8];
#pragma unroll
                for (int j = 0; j < 8; ++j) A[j] = cvt_pk(p[2 * j], p[2 * j + 1]);
                pl32swap(A[0], A[2]); pl32swap(A[1], A[3]);
                pl32swap(A[4], A[6]); pl32swap(A[5], A[7]);
                u32x4 f0v; f0v[0] = A[0]; f0v[1] = A[1]; f0v[2] = A[2]; f0v[3] = A[3];
                u32x4 f1v; f1v[0] = A[4]; f1v[1] = A[5]; f1v[2] = A[6]; f1v[3] = A[7];
                frg[g][0] = __builtin_bit_cast(bf16x8, f0v);
                frg[g][1] = __builtin_bit_cast(bf16x8, f1v);
            }
            __builtin_amdgcn_s_setprio(1);
#pragma unroll
            for (int ks2 = 0; ks2 < 2; ++ks2) {
                const int ksg = kb * 2 + ks2;
                bf16x8 vf0 = *(const bf16x8*)(Vbase + ksg * 512 + fragoff);
                bf16x8 vf1 = *(const bf16x8*)(Vbase + (4 + ksg) * 512 + fragoff);
                oacc[0][0] = MFMA32(vf0, frg[0][ks2], oacc[0][0]);
                oacc[0][1] = MFMA32(vf1, frg[0][ks2], oacc[0][1]);
                oacc[1][0] = MFMA32(vf0, frg[1][ks2], oacc[1][0]);
                oacc[1][1] = MFMA32(vf1, frg[1][ks2], oacc[1][1]);
            }
            __builtin_amdgcn_s_setprio(0);
        }
    }

    // ---- merge the two KV-halves (max-aware); mrgO reuses the 64KB KV buffer ----
    __syncthreads();
    float* mrgO = (float*)&KVb[0][0][0][0];  // [hi][val 0..31][row 0..127]
    const int row0 = qv_f * 64;              // + g*32 + la31
    if (half_f) {
#pragma unroll
        for (int g = 0; g < 2; ++g) {
            const int row = row0 + g * 32 + la31;
#pragma unroll
            for (int nt = 0; nt < 2; ++nt)
#pragma unroll
                for (int i = 0; i < 16; ++i)
                    mrgO[hi * 4096 + (nt * 16 + i) * 128 + row] = oacc[g][nt][i];
            mrgML[g][0][qv_f * 64 + lane] = m_run[g];   // per-lane m (pair lanes equal)
            mrgML[g][1][qv_f * 64 + lane] = l_run[g];
        }
    }
    __syncthreads();
    if (!half_f) {
#pragma unroll
        for (int g = 0; g < 2; ++g) {
            const int row = row0 + g * 32 + la31;
            const float m1 = mrgML[g][0][qv_f * 64 + lane];
            const float l1 = mrgML[g][1][qv_f * 64 + lane];
            const float mnew = fmaxf(m_run[g], m1);
            const float c0 = exp2f_fast(m_run[g] - mnew);
            const float c1 = exp2f_fast(m1 - mnew);
            float lt = l_run[g] * c0 + l1 * c1;
#pragma unroll
            for (int nt = 0; nt < 2; ++nt)
#pragma unroll
                for (int i = 0; i < 16; ++i)
                    oacc[g][nt][i] = oacc[g][nt][i] * c0 + mrgO[hi * 4096 + (nt * 16 + i) * 128 + row] * c1;
            const float l_tot = lt + __shfl_xor(lt, 32);
            const float inv = __builtin_amdgcn_rcpf(l_tot);
            float* obase = Og + ((size_t)(qtile * 128 + row) * NH + head) * DIM;
#pragma unroll
            for (int nt = 0; nt < 2; ++nt)
#pragma unroll
                for (int rq = 0; rq < 4; ++rq) {
                    float4 o;
                    o.x = oacc[g][nt][rq * 4 + 0] * inv;
                    o.y = oacc[g][nt][rq * 4 + 1] * inv;
                    o.z = oacc[g][nt][rq * 4 + 2] * inv;
                    o.w = oacc[g][nt][rq * 4 + 3] * inv;
                    *(float4*)(obase + nt * 32 + rq * 8 + hi * 4) = o;
                }
        }
    }
}

// ============ fallback (round-4 proven kernel) if ws too small ============
__global__ __launch_bounds__(256, 2)
void fb_kernel(const float* __restrict__ Qg, const float* __restrict__ Kg,
               const float* __restrict__ Vg, float* __restrict__ Og) {
    __shared__ unsigned short Kl[KVB][DIM];
    __shared__ unsigned short Vt[DIM][KVB];
    unsigned short* Kbase = &Kl[0][0];
    unsigned short* Vbase = &Vt[0][0];
    const int tid  = threadIdx.x;
    const int lane = tid & 63;
    const int wave = tid >> 6;
    const int la31 = lane & 31;
    const int hi   = lane >> 5;
    const int head  = blockIdx.x & 7;
    const int qtile = blockIdx.x >> 3;
    const int q     = qtile * 128 + wave * 32 + la31;
    bf16x8 qf[4];
#pragma unroll
    for (int kd = 0; kd < 4; ++kd) {
        const float* qp = Qg + ((size_t)q * NH + head) * DIM + kd * 16 + hi * 8;
        float4 a = ((const float4*)qp)[0];
        float4 b = ((const float4*)qp)[1];
        u32x4 w;
        w[0] = cvt_pk(a.x * SCL2, a.y * SCL2);
        w[1] = cvt_pk(a.z * SCL2, a.w * SCL2);
        w[2] = cvt_pk(b.x * SCL2, b.y * SCL2);
        w[3] = cvt_pk(b.z * SCL2, b.w * SCL2);
        qf[kd] = __builtin_bit_cast(bf16x8, w);
    }
    const int ksrow = tid & 63;
    const int kscol = (tid >> 6) * 16;
    const int vpair = tid & 31;
    const int vcg   = tid >> 5;
    const float* kptr  = Kg + ((size_t)ksrow * NH + head) * DIM + kscol;
    const float* vptr0 = Vg + ((size_t)(2 * vpair) * NH + head) * DIM + vcg * 8;
    const float* vptr1 = vptr0 + NH * DIM;
    constexpr size_t STRIDE = (size_t)KVB * NH * DIM;
    const int kIdx0 = swz(ksrow, kscol);
    const int kIdx1 = swz(ksrow, kscol + 8);
    f32x16 oacc[2];
#pragma unroll
    for (int nt = 0; nt < 2; ++nt)
#pragma unroll
        for (int i = 0; i < 16; ++i) oacc[nt][i] = 0.f;
    float m_run = -1e30f, l_run = 0.f;
    float4 kr0 = ((const float4*)kptr)[0], kr1 = ((const float4*)kptr)[1];
    float4 kr2 = ((const float4*)kptr)[2], kr3 = ((const float4*)kptr)[3];
    float4 va0 = ((const float4*)vptr0)[0], va1 = ((const float4*)vptr0)[1];
    float4 vb0 = ((const float4*)vptr1)[0], vb1 = ((const float4*)vptr1)[1];
    kptr += STRIDE; vptr0 += STRIDE; vptr1 += STRIDE;
    for (int t = 0; t < NT; ++t) {
        __syncthreads();
        {
            u32x4 w;
            w[0] = cvt_pk(kr0.x, kr0.y); w[1] = cvt_pk(kr0.z, kr0.w);
            w[2] = cvt_pk(kr1.x, kr1.y); w[3] = cvt_pk(kr1.z, kr1.w);
            *(u32x4*)(Kbase + kIdx0) = w;
            w[0] = cvt_pk(kr2.x, kr2.y); w[1] = cvt_pk(kr2.z, kr2.w);
            w[2] = cvt_pk(kr3.x, kr3.y); w[3] = cvt_pk(kr3.z, kr3.w);
            *(u32x4*)(Kbase + kIdx1) = w;
        }
        {
            *(unsigned*)(Vbase + swz(vcg * 8 + 0, 2 * vpair)) = cvt_pk(va0.x, vb0.x);
            *(unsigned*)(Vbase + swz(vcg * 8 + 1, 2 * vpair)) = cvt_pk(va0.y, vb0.y);
            *(unsigned*)(Vbase + swz(vcg * 8 + 2, 2 * vpair)) = cvt_pk(va0.z, vb0.z);
            *(unsigned*)(Vbase + swz(vcg * 8 + 3, 2 * vpair)) = cvt_pk(va0.w, vb0.w);
            *(unsigned*)(Vbase + swz(vcg * 8 + 4, 2 * vpair)) = cvt_pk(va1.x, vb1.x);
            *(unsigned*)(Vbase + swz(vcg * 8 + 5, 2 * vpair)) = cvt_pk(va1.y, vb1.y);
            *(unsigned*)(Vbase + swz(vcg * 8 + 6, 2 * vpair)) = cvt_pk(va1.z, vb1.z);
            *(unsigned*)(Vbase + swz(vcg * 8 + 7, 2 * vpair)) = cvt_pk(va1.w, vb1.w);
        }
        __syncthreads();
        if (t + 1 < NT) {
            kr0 = ((const float4*)kptr)[0]; kr1 = ((const float4*)kptr)[1];
            kr2 = ((const float4*)kptr)[2]; kr3 = ((const float4*)kptr)[3];
            va0 = ((const float4*)vptr0)[0]; va1 = ((const float4*)vptr0)[1];
            vb0 = ((const float4*)vptr1)[0]; vb1 = ((const float4*)vptr1)[1];
            kptr += STRIDE; vptr0 += STRIDE; vptr1 += STRIDE;
        }
        f32x16 s0, s1;
#pragma unroll
        for (int i = 0; i < 16; ++i) { s0[i] = 0.f; s1[i] = 0.f; }
        __builtin_amdgcn_s_setprio(1);
#pragma unroll
        for (int kd = 0; kd < 4; ++kd) {
            bf16x8 k0 = *(const bf16x8*)(Kbase + swz(la31, kd * 16 + hi * 8));
            bf16x8 k1 = *(const bf16x8*)(Kbase + swz(32 + la31, kd * 16 + hi * 8));
            s0 = MFMA32(k0, qf[kd], s0);
            s1 = MFMA32(k1, qf[kd], s1);
        }
        __builtin_amdgcn_s_setprio(0);
        float pmv[16];
#pragma unroll
        for (int i = 0; i < 16; ++i) pmv[i] = fmaxf(s0[i], s1[i]);
#pragma unroll
        for (int st = 8; st >= 1; st >>= 1)
#pragma unroll
            for (int i = 0; i < 8; ++i)
                if (i < st) pmv[i] = fmaxf(pmv[i], pmv[i + st]);
        float pm = pmv[0];
        pm = fmaxf(pm, __shfl_xor(pm, 32));
        if (__any(pm > m_run + 8.f)) {
            float mnew = fmaxf(m_run, pm);
            float corr = exp2f_fast(m_run - mnew);
            m_run = mnew;
            l_run *= corr;
#pragma unroll
            for (int i = 0; i < 16; ++i) { oacc[0][i] *= corr; oacc[1][i] *= corr; }
        }
#pragma unroll
        for (int kb = 0; kb < 2; ++kb) {
            const f32x16& s = kb ? s1 : s0;
            float p[16];
#pragma unroll
            for (int i = 0; i < 16; ++i) p[i] = exp2f_fast(s[i] - m_run);
            float ts[8];
#pragma unroll
            for (int i = 0; i < 8; ++i) ts[i] = p[i] + p[i + 8];
#pragma unroll
            for (int i = 0; i < 4; ++i) ts[i] += ts[i + 4];
            l_run += (ts[0] + ts[1]) + (ts[2] + ts[3]);
            unsigned A[8];
#pragma unroll
            for (int j = 0; j < 8; ++j) A[j] = cvt_pk(p[2 * j], p[2 * j + 1]);
            pl32swap(A[0], A[2]); pl32swap(A[1], A[3]);
            pl32swap(A[4], A[6]); pl32swap(A[5], A[7]);
            u32x4 f0v; f0v[0] = A[0]; f0v[1] = A[1]; f0v[2] = A[2]; f0v[3] = A[3];
            u32x4 f1v; f1v[0] = A[4]; f1v[1] = A[5]; f1v[2] = A[6]; f1v[3] = A[7];
            bf16x8 frag[2] = { __builtin_bit_cast(bf16x8, f0v), __builtin_bit_cast(bf16x8, f1v) };
            __builtin_amdgcn_s_setprio(1);
#pragma unroll
            for (int ksl = 0; ksl < 2; ++ksl) {
                const int ksg = kb * 2 + ksl;
                bf16x8 vf0 = *(const bf16x8*)(Vbase + swz(la31, ksg * 16 + hi * 8));
                bf16x8 vf1 = *(const bf16x8*)(Vbase + swz(32 + la31, ksg * 16 + hi * 8));
                oacc[0] = MFMA32(vf0, frag[ksl], oacc[0]);
                oacc[1] = MFMA32(vf1, frag[ksl], oacc[1]);
            }
            __builtin_amdgcn_s_setprio(0);
        }
    }
    {
        float l_tot = l_run + __shfl_xor(l_run, 32);
        float inv = __builtin_amdgcn_rcpf(l_tot);
        float* obase = Og + ((size_t)q * NH + head) * DIM;
#pragma unroll
        for (int nt = 0; nt < 2; ++nt)
#pragma unroll
            for (int rq = 0; rq < 4; ++rq) {
                float4 o;
                o.x = oacc[nt][rq * 4 + 0] * inv;
                o.y = oacc[nt][rq * 4 + 1] * inv;
                o.z = oacc[nt][rq * 4 + 2] * inv;
                o.w = oacc[nt][rq * 4 + 3] * inv;
                *(float4*)(obase + nt * 32 + rq * 8 + hi * 4) = o;
            }
    }
}

extern "C" void kernel_launch(void* const* d_in, const int* in_sizes, int n_in,
                              void* d_out, int out_size, void* d_ws, size_t ws_size,
                              hipStream_t stream) {
    const float* q = (const float*)d_in[0];
    const float* k = (const float*)d_in[1];
    const float* v = (const float*)d_in[2];
    float* out = (float*)d_out;
    constexpr size_t KV_WS = 2ull * NH * NT * SLAB * sizeof(unsigned short);  // 16.78 MB
    if (ws_size >= KV_WS) {
        unsigned short* Kws = (unsigned short*)d_ws;
        unsigned short* Vws = Kws + (size_t)NH * NT * SLAB;
        hipLaunchKernelGGL(prep_kernel, dim3(2048), dim3(256), 0, stream, k, v, Kws, Vws);
        // block = 256 threads = 4 waves = 2 KV-halves x 2 q-waves x 64 q-rows (QB=128)
        hipLaunchKernelGGL(fa_kernel, dim3(512), dim3(256), 0, stream, q, Kws, Vws, out);
    } else {
        hipLaunchKernelGGL(fb_kernel, dim3(512), dim3(256), 0, stream, q, k, v, out);
    }
}